// Round 11
// baseline (278.217 us; speedup 1.0000x reference)
//
#include <hip/hip_runtime.h>

// ---------------------------------------------------------------------------
// SegFormerXAttention on MI355X (gfx950)
//  B=4, Lv=1024, Lt=256, D=1024, H=16, DH=64, L=1280. fp32 in/out, int32 masks.
//  r21: attn LDS diet. r20's KVBLK=64 won (-12.6us total). Remaining attn
//  time is drain-stall dominated -> raise TLP: drop the 5KB kb_s LDS buffer
//  and compute key-mask bias inline from the int masks (r14-verified
//  mechanism, base-2 NEGB). LDS 37.9KB -> exactly 32KB = 5 blocks/CU
//  (was 4). Cost: 4 int4 L1-resident loads + 16 cndmask per warp-tile
//  (~noise on a ~7us VALU budget). proj CLOSED at r16-exact (~101us;
//  r12/r13/r17/r19 all regressed). cvt at traffic floor (~17us).
// ---------------------------------------------------------------------------

typedef __attribute__((ext_vector_type(8))) _Float16  half8;    // 8 x f16
typedef __attribute__((ext_vector_type(4))) _Float16  half4;    // 4 x f16
typedef __attribute__((ext_vector_type(4))) float     f32x4;
typedef __attribute__((ext_vector_type(4))) int       int4v;
typedef __attribute__((ext_vector_type(4))) unsigned int uint4v;
typedef __attribute__((ext_vector_type(2))) unsigned int uint2v;

#define MFMA_F16   __builtin_amdgcn_mfma_f32_16x16x32_f16
#define MFMA16_F16 __builtin_amdgcn_mfma_f32_16x16x16f16

#define LOG2E 1.4426950408889634f
#define NEGB  (-14426.950408889634f)   // -10000 * log2(e)

static __device__ __forceinline__ unsigned short f_to_f16u(float f) {
  _Float16 h = (_Float16)f;
  return __builtin_bit_cast(unsigned short, h);
}

#define GLOAD_LDS16(g, l)                                            \
  __builtin_amdgcn_global_load_lds(                                  \
      (const __attribute__((address_space(1))) void*)(g),            \
      (__attribute__((address_space(3))) void*)(l), 16, 0, 0)

// ---------------------------------------------------------------------------
// Pre-pass: fp32 -> fp16 elementwise (x2 unrolled)
// ---------------------------------------------------------------------------
struct CvtDesc { const float* src; unsigned short* dst; int n8; };
struct CvtArgs { CvtDesc d[14]; };

__global__ __launch_bounds__(256) void cvt_fp16(CvtArgs ca) {
  const CvtDesc dd = ca.d[blockIdx.y];
  const int n16 = dd.n8 >> 1;         // all sizes even
  const int stride = gridDim.x * blockDim.x;
  for (int i = blockIdx.x * blockDim.x + threadIdx.x; i < n16; i += stride) {
    const f32x4* src = (const f32x4*)dd.src + (size_t)i * 4;
    const f32x4 a = src[0];
    const f32x4 b = src[1];
    const f32x4 c = src[2];
    const f32x4 d = src[3];
    half8 h0, h1;
    h0[0] = (_Float16)a[0]; h0[1] = (_Float16)a[1];
    h0[2] = (_Float16)a[2]; h0[3] = (_Float16)a[3];
    h0[4] = (_Float16)b[0]; h0[5] = (_Float16)b[1];
    h0[6] = (_Float16)b[2]; h0[7] = (_Float16)b[3];
    h1[0] = (_Float16)c[0]; h1[1] = (_Float16)c[1];
    h1[2] = (_Float16)c[2]; h1[3] = (_Float16)c[3];
    h1[4] = (_Float16)d[0]; h1[5] = (_Float16)d[1];
    h1[6] = (_Float16)d[2]; h1[7] = (_Float16)d[3];
    half8* dst = (half8*)dd.dst + (size_t)i * 2;
    dst[0] = h0;
    dst[1] = h1;
  }
}

// ---------------------------------------------------------------------------
// Shared GEMM epilogue copy-out (nthr threads). Cs: row*128 + swizzled chunks.
//  mode 0 (Q): dst[((b*16+h)*Ld + soff + l)*64 + dh]   (linear, seq-major)
//  mode 2 (K): dst[bh*81920 + (k>>4)*1024 + (dh>>5)*512 + (k&15)*32
//                   + ((dh>>3)&3)*8 + (dh&7)]           (1KB-contig tiles)
//  mode 1 (V): dst[bh*81920 + (k>>5)*2048 + dh*32 + p], tile positions p
//              permuted: p = q*8+j holds key 4q + (j&3) + 16*(j>>2)
// ---------------------------------------------------------------------------
static __device__ __forceinline__ void copy_out_tile(
    const unsigned short* Cs, unsigned short* dst, int tid, int nthr,
    int b, int l0, int h0, int Ld, int soff, int mode) {
  for (int c = tid; c < 2048; c += nthr) {
    const int major = c >> 4;                // mode0/2: l-local; mode1: dh-local
    const int kc    = c & 15;
    if (mode == 1) {
      const int base = (kc >> 2) * 32 + (kc & 3) * 4;
      const int sw   = major & 7;
      const int o1   = major * 128 + (((base >> 3) ^ sw) << 3) + (base & 7);
      const int b2   = base + 16;
      const int o2   = major * 128 + (((b2 >> 3) ^ sw) << 3) + (b2 & 7);
      const uint2v lo = *(const uint2v*)&Cs[o1];
      const uint2v hi = *(const uint2v*)&Cs[o2];
      uint4v val; val[0] = lo[0]; val[1] = lo[1]; val[2] = hi[0]; val[3] = hi[1];
      const int hh = h0 + (major >> 6);
      const int dh = major & 63;
      const int k  = soff + l0 + (kc >> 2) * 32;
      const size_t el = (size_t)(b * 16 + hh) * 81920 + (size_t)(k >> 5) * 2048 +
                        dh * 32 + (kc & 3) * 8;
      *(uint4v*)(dst + el) = val;
    } else {
      const uint4v val =
          *(const uint4v*)&Cs[major * 128 + ((kc ^ (major & 7)) << 3)];
      if (mode == 0) {
        const size_t el =
            ((size_t)(b * 16 + h0 + (kc >> 3)) * Ld + soff + l0 + major) * 64 +
            (kc & 7) * 8;
        *(uint4v*)(dst + el) = val;
      } else {  // mode 2
        const int k   = soff + l0 + major;
        const int dh0 = (kc & 7) * 8;
        const size_t el = (size_t)(b * 16 + h0 + (kc >> 3)) * 81920 +
                          (size_t)(k >> 4) * 1024 + (dh0 >> 5) * 512 +
                          (k & 15) * 32 + ((dh0 >> 3) & 3) * 8;
        *(uint4v*)(dst + el) = val;
      }
    }
  }
}

// ---------------------------------------------------------------------------
// Projection GEMM (fp16 inputs) — r16-exact (measured 101us): 128x128 tile,
// 2-barrier stage->drain->compute, Cs stride 128 (32KB LDS), oscale on Q.
// ---------------------------------------------------------------------------
struct ProjDescH {
  const unsigned short* X;
  const unsigned short* W;
  const float* Bv;
  unsigned short* dst;
  int M, lxsh, Ld, soff, mode;
  float oscale;
};
struct ProjArgsH { ProjDescH d[12]; };

__global__ __launch_bounds__(256) void proj_gemm_h(ProjArgsH pa) {
  const ProjDescH dd = pa.d[blockIdx.z];
  const int m0 = blockIdx.y * 128;
  if (m0 >= dd.M) return;
  const int n0 = blockIdx.x * 128;

  __shared__ __align__(16) unsigned char smem[32768];
  unsigned short* As = (unsigned short*)smem;
  unsigned short* Bs = As + 4096;
  unsigned short* Cs = (unsigned short*)smem;

  const int tid  = threadIdx.x;
  const int lane = tid & 63;
  const int w    = tid >> 6;
  const int wr   = (w >> 1) * 64;
  const int wc   = (w & 1) * 64;
  const int ql   = lane & 15;
  const int qd   = lane >> 4;

  f32x4 acc[4][4];
  for (int i = 0; i < 4; ++i)
    for (int j = 0; j < 4; ++j) acc[i][j] = (f32x4)(0.0f);

  const unsigned short* Xg = dd.X + (size_t)m0 * 1024;
  const unsigned short* Wg = dd.W + (size_t)n0 * 1024;

  for (int k0 = 0; k0 < 1024; k0 += 32) {
    __syncthreads();
    for (int half = 0; half < 2; ++half) {
      const int cb  = w * 128 + half * 64;
      const int c   = cb + lane;
      const int row = c >> 2;
      const int kcg = (c & 3) ^ (row & 3);
      GLOAD_LDS16(Xg + row * 1024 + k0 + kcg * 8, As + cb * 8);
      GLOAD_LDS16(Wg + row * 1024 + k0 + kcg * 8, Bs + cb * 8);
    }
    __syncthreads();

    half8 af[4], bf[4];
    for (int mt = 0; mt < 4; ++mt) {
      const int row = wr + mt * 16 + ql;
      af[mt] = *(const half8*)&As[row * 32 + ((qd ^ (row & 3)) << 3)];
    }
    for (int nt = 0; nt < 4; ++nt) {
      const int row = wc + nt * 16 + ql;
      bf[nt] = *(const half8*)&Bs[row * 32 + ((qd ^ (row & 3)) << 3)];
    }
    for (int mt = 0; mt < 4; ++mt)
      for (int nt = 0; nt < 4; ++nt)
        acc[mt][nt] = MFMA_F16(af[mt], bf[nt], acc[mt][nt], 0, 0, 0);
  }

  float bv[4];
  for (int nt = 0; nt < 4; ++nt)
    bv[nt] = dd.Bv[n0 + wc + nt * 16 + ql];

  __syncthreads();

  for (int mt = 0; mt < 4; ++mt) {
    for (int nt = 0; nt < 4; ++nt) {
      const int nl = wc + nt * 16 + ql;
      for (int r = 0; r < 4; ++r) {
        const int ml = wr + mt * 16 + qd * 4 + r;
        const int row = dd.mode == 1 ? nl : ml;
        const int col = dd.mode == 1 ? ml : nl;
        const float v = (acc[mt][nt][r] + bv[nt]) * dd.oscale;
        Cs[row * 128 + (((col >> 3) ^ (row & 7)) << 3) + (col & 7)] = f_to_f16u(v);
      }
    }
  }
  __syncthreads();

  copy_out_tile(Cs, dd.dst, tid, 256, m0 >> dd.lxsh, m0 & ((1 << dd.lxsh) - 1),
                n0 >> 6, dd.Ld, dd.soff, dd.mode);
}

// ---------------------------------------------------------------------------
// Fallback fp32-input GEMM for small ws_size (same output layouts)
// ---------------------------------------------------------------------------
struct ProjDesc {
  const float* X;
  const float* W;
  const float* Bv;
  unsigned short* dst;
  int M, lxsh, Ld, soff, mode;
  float oscale;
};
struct ProjArgs { ProjDesc d[12]; };

static __device__ __forceinline__ half8 cvt8sw(const float* base, int row, int g0) {
  const int sw = row & 7;
  const f32x4 a = *(const f32x4*)(base + (row * 8 + (g0 ^ sw)) * 4);
  const f32x4 b = *(const f32x4*)(base + (row * 8 + ((g0 + 1) ^ sw)) * 4);
  half8 h;
  h[0] = (_Float16)a[0]; h[1] = (_Float16)a[1];
  h[2] = (_Float16)a[2]; h[3] = (_Float16)a[3];
  h[4] = (_Float16)b[0]; h[5] = (_Float16)b[1];
  h[6] = (_Float16)b[2]; h[7] = (_Float16)b[3];
  return h;
}

__global__ __launch_bounds__(256) void proj_gemm_f32(ProjArgs pa) {
  const ProjDesc dd = pa.d[blockIdx.z];
  const int m0 = blockIdx.y * 128;
  if (m0 >= dd.M) return;
  const int n0 = blockIdx.x * 128;

  __shared__ __align__(16) unsigned char smem[32768];
  float* As = (float*)smem;
  float* Bs = As + 4096;
  unsigned short* Cs = (unsigned short*)smem;

  const int tid  = threadIdx.x;
  const int lane = tid & 63;
  const int w    = tid >> 6;
  const int wr   = (w >> 1) * 64;
  const int wc   = (w & 1) * 64;
  const int ql   = lane & 15;
  const int qd   = lane >> 4;

  f32x4 acc[4][4];
  for (int i = 0; i < 4; ++i)
    for (int j = 0; j < 4; ++j) acc[i][j] = (f32x4)(0.0f);

  const float* Xg = dd.X + (size_t)m0 * 1024;
  const float* Wg = dd.W + (size_t)n0 * 1024;

  for (int k0 = 0; k0 < 1024; k0 += 32) {
    __syncthreads();
    for (int j = 0; j < 4; ++j) {
      const int cb  = (j * 4 + w) * 64;
      const int c   = cb + lane;
      const int row = c >> 3;
      const int kcg = (c & 7) ^ (row & 7);
      GLOAD_LDS16(Xg + row * 1024 + k0 + kcg * 4, As + cb * 4);
      GLOAD_LDS16(Wg + row * 1024 + k0 + kcg * 4, Bs + cb * 4);
    }
    __syncthreads();

    half8 af[4], bf[4];
    for (int mt = 0; mt < 4; ++mt)
      af[mt] = cvt8sw(As, wr + mt * 16 + ql, qd * 2);
    for (int nt = 0; nt < 4; ++nt)
      bf[nt] = cvt8sw(Bs, wc + nt * 16 + ql, qd * 2);
    for (int mt = 0; mt < 4; ++mt)
      for (int nt = 0; nt < 4; ++nt)
        acc[mt][nt] = MFMA_F16(af[mt], bf[nt], acc[mt][nt], 0, 0, 0);
  }

  float bv[4];
  for (int nt = 0; nt < 4; ++nt)
    bv[nt] = dd.Bv[n0 + wc + nt * 16 + ql];

  __syncthreads();

  for (int mt = 0; mt < 4; ++mt) {
    for (int nt = 0; nt < 4; ++nt) {
      const int nl = wc + nt * 16 + ql;
      for (int r = 0; r < 4; ++r) {
        const int ml = wr + mt * 16 + qd * 4 + r;
        const int row = dd.mode == 1 ? nl : ml;
        const int col = dd.mode == 1 ? ml : nl;
        const float v = (acc[mt][nt][r] + bv[nt]) * dd.oscale;
        Cs[row * 128 + (((col >> 3) ^ (row & 7)) << 3) + (col & 7)] = f_to_f16u(v);
      }
    }
  }
  __syncthreads();

  copy_out_tile(Cs, dd.dst, tid, 256, m0 >> dd.lxsh, m0 & ((1 << dd.lxsh) - 1),
                n0 >> 6, dd.Ld, dd.soff, dd.mode);
}

// ---------------------------------------------------------------------------
// Flash attention v9: 64 q/block, KVBLK=64 (20 tiles), K/V dbuf LDS = exactly
// 32KB -> 5 blocks/CU. Key-mask bias computed INLINE from int masks (L1-
// resident; r14-verified mechanism, base-2 NEGB). XCD swizzle, base-2 softmax.
// ---------------------------------------------------------------------------
__global__ __launch_bounds__(256) void attn_flash9(
    const unsigned short* __restrict__ Qa_v, const unsigned short* __restrict__ Qb_v,
    const unsigned short* __restrict__ K_v,  const unsigned short* __restrict__ V_vT,
    const unsigned short* __restrict__ Qa_t, const unsigned short* __restrict__ Qb_t,
    const unsigned short* __restrict__ K_t,  const unsigned short* __restrict__ V_tT,
    const int* __restrict__ vmask, const int* __restrict__ tmask,
    float* __restrict__ out_v, float* __restrict__ out_t) {
  __shared__ __align__(16) unsigned short KVs[16384];  // 2 bufs x 8192 = 32KB

  // XCD-contiguous swizzle: 1280 % 8 == 0 -> bijective. XCD x gets 8
  // consecutive bh -> 2.56MB K/V, L2-resident.
  const int bid = blockIdx.x;
  const int sid = (bid & 7) * 160 + (bid >> 3);
  const int bh  = sid / 20;
  const int sub = sid - bh * 20;

  const bool vside = sub < 16;
  const int  Lq    = vside ? 1024 : 256;
  const int  qblk  = vside ? sub : sub - 16;
  const unsigned short* Qa = vside ? Qa_v : Qa_t;
  const unsigned short* Qb = vside ? Qb_v : Qb_t;
  const unsigned short* K  = vside ? K_v  : K_t;
  const unsigned short* VT = vside ? V_vT : V_tT;
  const int* mq  = vside ? vmask : tmask;
  float*     out = vside ? out_v : out_t;

  const int b = bh >> 4;
  const int h = bh & 15;
  const int tid  = threadIdx.x;
  const int w    = tid >> 6;
  const int lane = tid & 63;
  const int ql = lane & 15, qd = lane >> 4;
  const int q0 = qblk * 64 + w * 16;

  const unsigned short* Kb = K  + (size_t)bh * 81920;
  const unsigned short* Vb = VT + (size_t)bh * 81920;
  const int* kmv = vmask + b * 1024;   // key masks (inline bias; L1-resident)
  const int* kmt = tmask + b * 256;

  const int gsw  = (tid ^ ((tid >> 3) & 3)) * 8;  // per-lane global offs (halfs)
  const int wlds = w * 512;                       // wave-uniform LDS base (halfs)

  // 64-key tile: K = 4 contiguous 16-key subtiles (4096 halfs), V = 2
  // contiguous 32-key groups (4096 halfs). Chunk permutation c^((c>>3)&3)
  // is invariant under +256-chunk offsets (bit 8 doesn't reach bits 3-4).
#define STAGE8(nb, k0s)                                                     \
  do {                                                                      \
    const unsigned short* Kt_ = Kb + (size_t)((k0s) >> 4) * 1024;           \
    const unsigned short* Vt_ = Vb + (size_t)((k0s) >> 5) * 2048;           \
    unsigned short* Ld_ = KVs + (nb) * 8192 + wlds;                         \
    GLOAD_LDS16(Kt_ + gsw, Ld_);                                            \
    GLOAD_LDS16(Kt_ + 2048 + gsw, Ld_ + 2048);                              \
    GLOAD_LDS16(Vt_ + gsw, Ld_ + 4096);                                     \
    GLOAD_LDS16(Vt_ + 2048 + gsw, Ld_ + 6144);                              \
  } while (0)

  STAGE8(0, 0);  // prefetch tile 0 while we load Q

  const unsigned short* Qab = Qa + ((size_t)bh * Lq + q0) * 64;
  const unsigned short* Qbb = Qb + ((size_t)bh * Lq + q0) * 64;
  half8 aA[2], aB[2];
  for (int ks = 0; ks < 2; ++ks) {
    aA[ks] = *(const half8*)&Qab[ql * 64 + ks * 32 + qd * 8];
    aB[ks] = *(const half8*)&Qbb[ql * 64 + ks * 32 + qd * 8];
  }
  const int mqs = mq[b * Lq + q0 + ql];

  const int swc = (qd ^ ((ql >> 1) & 3)) * 8;  // read-side chunk XOR (halfs)

  float m = -1e30f, l = 0.0f;
  f32x4 o[4];
  for (int nt = 0; nt < 4; ++nt) o[nt] = (f32x4)(0.0f);

  int cur = 0;
  // tile body; QF = Q fragment pair; KM = key-mask base for this tile
#define TILE9(tt, QF, KM)                                                   \
  {                                                                         \
    __syncthreads();                /* buf[cur] staged (vmcnt drained) */    \
    if ((tt) < 19) STAGE8(cur ^ 1, ((tt) + 1) * 64);                        \
    const unsigned short* Ls = KVs + cur * 8192;                            \
    half8 va[4], vb2[4];                                                    \
    for (int nt = 0; nt < 4; ++nt) {                                        \
      va[nt]  = *(const half8*)&Ls[4096 + (nt * 16 + ql) * 32 + swc];       \
      vb2[nt] = *(const half8*)&Ls[6144 + (nt * 16 + ql) * 32 + swc];       \
    }                                                                       \
    f32x4 sv[4];                                                            \
    for (int s = 0; s < 4; ++s) {                                           \
      const int4v mi = *(const int4v*)((KM) + s * 16 + qd * 4);             \
      f32x4 S;                                                              \
      for (int r = 0; r < 4; ++r) S[r] = mi[r] ? 0.0f : NEGB;               \
      const unsigned short* Kt = Ls + s * 1024;                             \
      const half8 kf0 = *(const half8*)&Kt[ql * 32 + swc];                  \
      const half8 kf1 = *(const half8*)&Kt[512 + ql * 32 + swc];            \
      S = MFMA_F16(kf0, QF[0], S, 0, 0, 0);                                 \
      S = MFMA_F16(kf1, QF[1], S, 0, 0, 0);                                 \
      for (int r = 0; r < 4; ++r) sv[s][r] = mqs ? S[r] : NEGB;             \
    }                                                                       \
    const float b0 = fmaxf(fmaxf(sv[0][0], sv[0][1]), fmaxf(sv[0][2], sv[0][3])); \
    const float b1 = fmaxf(fmaxf(sv[1][0], sv[1][1]), fmaxf(sv[1][2], sv[1][3])); \
    const float b2 = fmaxf(fmaxf(sv[2][0], sv[2][1]), fmaxf(sv[2][2], sv[2][3])); \
    const float b3 = fmaxf(fmaxf(sv[3][0], sv[3][1]), fmaxf(sv[3][2], sv[3][3])); \
    float bm = fmaxf(fmaxf(b0, b1), fmaxf(b2, b3));                         \
    bm = fmaxf(bm, __shfl_xor(bm, 16, 64));                                 \
    bm = fmaxf(bm, __shfl_xor(bm, 32, 64));                                 \
    if (__any(bm > m)) {            /* THR=0 defer-max: exact */            \
      const float nm = fmaxf(m, bm);                                        \
      const float alpha = __builtin_amdgcn_exp2f(m - nm);                   \
      l *= alpha;                                                           \
      for (int nt = 0; nt < 4; ++nt)                                        \
        for (int r = 0; r < 4; ++r) o[nt][r] *= alpha;                      \
      m = nm;                                                               \
    }                                                                       \
    half4 pv[4];                                                            \
    float lsum = 0.0f;                                                      \
    for (int s = 0; s < 4; ++s)                                             \
      for (int r = 0; r < 4; ++r) {                                         \
        const float p = __builtin_amdgcn_exp2f(sv[s][r] - m);               \
        lsum += p;                                                          \
        pv[s][r] = (_Float16)p;                                             \
      }                                                                     \
    l += lsum;                                                              \
    for (int nt = 0; nt < 4; ++nt) {                                        \
      const half4 alo = __builtin_shufflevector(va[nt], va[nt], 0, 1, 2, 3);   \
      const half4 ahi = __builtin_shufflevector(va[nt], va[nt], 4, 5, 6, 7);   \
      const half4 blo = __builtin_shufflevector(vb2[nt], vb2[nt], 0, 1, 2, 3); \
      const half4 bhi = __builtin_shufflevector(vb2[nt], vb2[nt], 4, 5, 6, 7); \
      o[nt] = MFMA16_F16(alo, pv[0], o[nt], 0, 0, 0);                       \
      o[nt] = MFMA16_F16(ahi, pv[1], o[nt], 0, 0, 0);                       \
      o[nt] = MFMA16_F16(blo, pv[2], o[nt], 0, 0, 0);                       \
      o[nt] = MFMA16_F16(bhi, pv[3], o[nt], 0, 0, 0);                       \
    }                                                                       \
    cur ^= 1;                                                               \
  }

  for (int t = 0; t < 16; ++t) TILE9(t, aA, kmv + t * 64);       // vid keys
  for (int t = 16; t < 20; ++t) TILE9(t, aB, kmt + (t - 16) * 64); // txt keys
#undef TILE9
#undef STAGE8

  // per-warp epilogue: reduce l over qd lanes (keys split across qd in S^T)
  l += __shfl_xor(l, 16, 64);
  l += __shfl_xor(l, 32, 64);
  const float inv = 0.125f / l;

  float* ob = out + ((size_t)(b * Lq + q0 + ql)) * 1024 + h * 64;
  for (int nt = 0; nt < 4; ++nt) {
    f32x4 r;
    for (int j = 0; j < 4; ++j) r[j] = o[nt][j] * inv;
    *(f32x4*)(ob + nt * 16 + qd * 4) = r;
  }
}

// ---------------------------------------------------------------------------
extern "C" void kernel_launch(void* const* d_in, const int* in_sizes, int n_in,
                              void* d_out, int out_size, void* d_ws, size_t ws_size,
                              hipStream_t stream) {
  const float* vid   = (const float*)d_in[0];
  const int*   vmask = (const int*)d_in[1];
  const float* txt   = (const float*)d_in[2];
  const int*   tmask = (const int*)d_in[3];
  const float* Wsrc[4] = {(const float*)d_in[4], (const float*)d_in[6],
                          (const float*)d_in[8], (const float*)d_in[10]};
  const float* Bsrc[4] = {(const float*)d_in[5], (const float*)d_in[7],
                          (const float*)d_in[9], (const float*)d_in[11]};

  const int DD = 1024 * 1024, Dm = 1024, MEG = 1048576;

  unsigned short* ws = (unsigned short*)d_ws;
  unsigned short* Qa_v = ws;                       // 4,194,304 halfs
  unsigned short* Qb_v = ws + 4194304;
  unsigned short* K_v  = ws + 8388608;             // 5,242,880
  unsigned short* V_vT = ws + 13631488;
  unsigned short* Qa_t = ws + 18874368;            // 1,048,576
  unsigned short* Qb_t = ws + 19922944;
  unsigned short* K_t  = ws + 20971520;            // 5,242,880
  unsigned short* V_tT = ws + 26214400;            // end 31,457,280
  unsigned short* Xv_h = ws + 31457280;            // 4,194,304 (dead after proj)
  unsigned short* Xt_h = ws + 35651584;            // 1,048,576
  unsigned short* Wh   = ws + 36700160;            // 12 MEG -> end 49,283,072

  const size_t need = (size_t)49283072 * 2;
  const bool use_h = ws_size >= need;

  if (use_h) {
    CvtArgs ca;
    ca.d[0] = CvtDesc{vid, Xv_h, 4194304 / 8};
    ca.d[1] = CvtDesc{txt, Xt_h, 1048576 / 8};
    for (int s = 0; s < 4; ++s)
      for (int j = 0; j < 3; ++j)
        ca.d[2 + s * 3 + j] = CvtDesc{Wsrc[s] + j * DD, Wh + (s * 3 + j) * MEG, DD / 8};
    cvt_fp16<<<dim3(256, 14), dim3(256), 0, stream>>>(ca);

    ProjArgsH pa;
    auto set = [&](int i, const unsigned short* X, int wi, const float* Bv,
                   unsigned short* dst, int M, int lxsh, int Ld, int soff, int mode,
                   float osc) {
      pa.d[i] = ProjDescH{X, Wh + wi * MEG, Bv, dst, M, lxsh, Ld, soff, mode, osc};
    };
    //    idx  X     Wi  bias          dst    M     lxsh Ld    soff  mode  oscale
    set(0,  Xv_h, 0,  Bsrc[0],          Qa_v, 4096, 10, 1024, 0,    0, LOG2E);
    set(1,  Xv_h, 1,  Bsrc[0] + Dm,     K_v,  4096, 10, 1280, 0,    2, 1.0f);
    set(2,  Xv_h, 2,  Bsrc[0] + 2 * Dm, V_vT, 4096, 10, 1280, 0,    1, 1.0f);
    set(3,  Xv_h, 3,  Bsrc[1],          Qb_v, 4096, 10, 1024, 0,    0, LOG2E);
    set(4,  Xt_h, 4,  Bsrc[1] + Dm,     K_v,  1024, 8,  1280, 1024, 2, 1.0f);
    set(5,  Xt_h, 5,  Bsrc[1] + 2 * Dm, V_vT, 1024, 8,  1280, 1024, 1, 1.0f);
    set(6,  Xt_h, 6,  Bsrc[2],          Qa_t, 1024, 8,  256,  0,    0, LOG2E);
    set(7,  Xv_h, 7,  Bsrc[2] + Dm,     K_t,  4096, 10, 1280, 0,    2, 1.0f);
    set(8,  Xv_h, 8,  Bsrc[2] + 2 * Dm, V_tT, 4096, 10, 1280, 0,    1, 1.0f);
    set(9,  Xt_h, 9,  Bsrc[3],          Qb_t, 1024, 8,  256,  0,    0, LOG2E);
    set(10, Xt_h, 10, Bsrc[3] + Dm,     K_t,  1024, 8,  1280, 1024, 2, 1.0f);
    set(11, Xt_h, 11, Bsrc[3] + 2 * Dm, V_tT, 1024, 8,  1280, 1024, 1, 1.0f);

    proj_gemm_h<<<dim3(8, 32, 12), dim3(256), 0, stream>>>(pa);
  } else {
    ProjArgs pa;
    auto set = [&](int i, const float* X, const float* W, const float* Bv,
                   unsigned short* dst, int M, int lxsh, int Ld, int soff, int mode,
                   float osc) {
      pa.d[i] = ProjDesc{X, W, Bv, dst, M, lxsh, Ld, soff, mode, osc};
    };
    set(0,  vid, Wsrc[0],          Bsrc[0],          Qa_v, 4096, 10, 1024, 0,    0, LOG2E);
    set(1,  vid, Wsrc[0] + DD,     Bsrc[0] + Dm,     K_v,  4096, 10, 1280, 0,    2, 1.0f);
    set(2,  vid, Wsrc[0] + 2 * DD, Bsrc[0] + 2 * Dm, V_vT, 4096, 10, 1280, 0,    1, 1.0f);
    set(3,  vid, Wsrc[1],          Bsrc[1],          Qb_v, 4096, 10, 1024, 0,    0, LOG2E);
    set(4,  txt, Wsrc[1] + DD,     Bsrc[1] + Dm,     K_v,  1024, 8,  1280, 1024, 2, 1.0f);
    set(5,  txt, Wsrc[1] + 2 * DD, Bsrc[1] + 2 * Dm, V_vT, 1024, 8,  1280, 1024, 1, 1.0f);
    set(6,  txt, Wsrc[2],          Bsrc[2],          Qa_t, 1024, 8,  256,  0,    0, LOG2E);
    set(7,  vid, Wsrc[2] + DD,     Bsrc[2] + Dm,     K_t,  4096, 10, 1280, 0,    2, 1.0f);
    set(8,  vid, Wsrc[2] + 2 * DD, Bsrc[2] + 2 * Dm, V_tT, 4096, 10, 1280, 0,    1, 1.0f);
    set(9,  txt, Wsrc[3],          Bsrc[3],          Qb_t, 1024, 8,  256,  0,    0, LOG2E);
    set(10, txt, Wsrc[3] + DD,     Bsrc[3] + Dm,     K_t,  1024, 8,  1280, 1024, 2, 1.0f);
    set(11, txt, Wsrc[3] + 2 * DD, Bsrc[3] + 2 * Dm, V_tT, 1024, 8,  1280, 1024, 1, 1.0f);

    proj_gemm_f32<<<dim3(8, 32, 12), dim3(256), 0, stream>>>(pa);
  }

  float* out_v = (float*)d_out;
  float* out_t = out_v + 4 * 1024 * 1024;
  attn_flash9<<<dim3(1280), dim3(256), 0, stream>>>(
      Qa_v, Qb_v, K_v, V_vT, Qa_t, Qb_t, K_t, V_tT,
      vmask, tmask, out_v, out_t);
}

// Round 12
// 270.760 us; speedup vs baseline: 1.0275x; 1.0275x over previous
//
#include <hip/hip_runtime.h>

// ---------------------------------------------------------------------------
// SegFormerXAttention on MI355X (gfx950)
//  B=4, Lv=1024, Lt=256, D=1024, H=16, DH=64, L=1280. fp32 in/out, int32 masks.
//  r22: FINAL = r20-exact restore (session best, 274.3us measured).
//  r21's attn LDS-diet (inline mask bias, 32KB LDS) regressed 274->278:
//  attn was not LDS-occupancy-limited and the inline mask loads sat on the
//  softmax critical path. Reverted per pre-commitment.
//  Session summary:
//   - attn: XCD-swizzle + 64q/block + LDS dbuf (r11), exp2 base-change +
//     LDS key-bias + loop split (r15), KVBLK=64 (r20). ~130 -> ~70us.
//   - proj: Cs-128 (r16). 2-barrier 128x128 loop is a verified local
//     optimum (r12/r13/r17/r19 restructures all regressed). ~101us.
//   - cvt at traffic floor ~17us; ~85us fixed harness overhead.
// ---------------------------------------------------------------------------

typedef __attribute__((ext_vector_type(8))) _Float16  half8;    // 8 x f16
typedef __attribute__((ext_vector_type(4))) _Float16  half4;    // 4 x f16
typedef __attribute__((ext_vector_type(4))) float     f32x4;
typedef __attribute__((ext_vector_type(4))) unsigned int uint4v;
typedef __attribute__((ext_vector_type(2))) unsigned int uint2v;

#define MFMA_F16   __builtin_amdgcn_mfma_f32_16x16x32_f16
#define MFMA16_F16 __builtin_amdgcn_mfma_f32_16x16x16f16

#define LOG2E 1.4426950408889634f
#define NEGB  (-14426.950408889634f)   // -10000 * log2(e)

static __device__ __forceinline__ unsigned short f_to_f16u(float f) {
  _Float16 h = (_Float16)f;
  return __builtin_bit_cast(unsigned short, h);
}

#define GLOAD_LDS16(g, l)                                            \
  __builtin_amdgcn_global_load_lds(                                  \
      (const __attribute__((address_space(1))) void*)(g),            \
      (__attribute__((address_space(3))) void*)(l), 16, 0, 0)

// ---------------------------------------------------------------------------
// Pre-pass: fp32 -> fp16 elementwise (x2 unrolled)
// ---------------------------------------------------------------------------
struct CvtDesc { const float* src; unsigned short* dst; int n8; };
struct CvtArgs { CvtDesc d[14]; };

__global__ __launch_bounds__(256) void cvt_fp16(CvtArgs ca) {
  const CvtDesc dd = ca.d[blockIdx.y];
  const int n16 = dd.n8 >> 1;         // all sizes even
  const int stride = gridDim.x * blockDim.x;
  for (int i = blockIdx.x * blockDim.x + threadIdx.x; i < n16; i += stride) {
    const f32x4* src = (const f32x4*)dd.src + (size_t)i * 4;
    const f32x4 a = src[0];
    const f32x4 b = src[1];
    const f32x4 c = src[2];
    const f32x4 d = src[3];
    half8 h0, h1;
    h0[0] = (_Float16)a[0]; h0[1] = (_Float16)a[1];
    h0[2] = (_Float16)a[2]; h0[3] = (_Float16)a[3];
    h0[4] = (_Float16)b[0]; h0[5] = (_Float16)b[1];
    h0[6] = (_Float16)b[2]; h0[7] = (_Float16)b[3];
    h1[0] = (_Float16)c[0]; h1[1] = (_Float16)c[1];
    h1[2] = (_Float16)c[2]; h1[3] = (_Float16)c[3];
    h1[4] = (_Float16)d[0]; h1[5] = (_Float16)d[1];
    h1[6] = (_Float16)d[2]; h1[7] = (_Float16)d[3];
    half8* dst = (half8*)dd.dst + (size_t)i * 2;
    dst[0] = h0;
    dst[1] = h1;
  }
}

// ---------------------------------------------------------------------------
// Shared GEMM epilogue copy-out (nthr threads). Cs: row*128 + swizzled chunks.
//  mode 0 (Q): dst[((b*16+h)*Ld + soff + l)*64 + dh]   (linear, seq-major)
//  mode 2 (K): dst[bh*81920 + (k>>4)*1024 + (dh>>5)*512 + (k&15)*32
//                   + ((dh>>3)&3)*8 + (dh&7)]           (1KB-contig tiles)
//  mode 1 (V): dst[bh*81920 + (k>>5)*2048 + dh*32 + p], tile positions p
//              permuted: p = q*8+j holds key 4q + (j&3) + 16*(j>>2)
// ---------------------------------------------------------------------------
static __device__ __forceinline__ void copy_out_tile(
    const unsigned short* Cs, unsigned short* dst, int tid, int nthr,
    int b, int l0, int h0, int Ld, int soff, int mode) {
  for (int c = tid; c < 2048; c += nthr) {
    const int major = c >> 4;                // mode0/2: l-local; mode1: dh-local
    const int kc    = c & 15;
    if (mode == 1) {
      const int base = (kc >> 2) * 32 + (kc & 3) * 4;
      const int sw   = major & 7;
      const int o1   = major * 128 + (((base >> 3) ^ sw) << 3) + (base & 7);
      const int b2   = base + 16;
      const int o2   = major * 128 + (((b2 >> 3) ^ sw) << 3) + (b2 & 7);
      const uint2v lo = *(const uint2v*)&Cs[o1];
      const uint2v hi = *(const uint2v*)&Cs[o2];
      uint4v val; val[0] = lo[0]; val[1] = lo[1]; val[2] = hi[0]; val[3] = hi[1];
      const int hh = h0 + (major >> 6);
      const int dh = major & 63;
      const int k  = soff + l0 + (kc >> 2) * 32;
      const size_t el = (size_t)(b * 16 + hh) * 81920 + (size_t)(k >> 5) * 2048 +
                        dh * 32 + (kc & 3) * 8;
      *(uint4v*)(dst + el) = val;
    } else {
      const uint4v val =
          *(const uint4v*)&Cs[major * 128 + ((kc ^ (major & 7)) << 3)];
      if (mode == 0) {
        const size_t el =
            ((size_t)(b * 16 + h0 + (kc >> 3)) * Ld + soff + l0 + major) * 64 +
            (kc & 7) * 8;
        *(uint4v*)(dst + el) = val;
      } else {  // mode 2
        const int k   = soff + l0 + major;
        const int dh0 = (kc & 7) * 8;
        const size_t el = (size_t)(b * 16 + h0 + (kc >> 3)) * 81920 +
                          (size_t)(k >> 4) * 1024 + (dh0 >> 5) * 512 +
                          (k & 15) * 32 + ((dh0 >> 3) & 3) * 8;
        *(uint4v*)(dst + el) = val;
      }
    }
  }
}

// ---------------------------------------------------------------------------
// Projection GEMM (fp16 inputs) — r16-exact (measured 101us): 128x128 tile,
// 2-barrier stage->drain->compute, Cs stride 128 (32KB LDS), oscale on Q.
// ---------------------------------------------------------------------------
struct ProjDescH {
  const unsigned short* X;
  const unsigned short* W;
  const float* Bv;
  unsigned short* dst;
  int M, lxsh, Ld, soff, mode;
  float oscale;
};
struct ProjArgsH { ProjDescH d[12]; };

__global__ __launch_bounds__(256) void proj_gemm_h(ProjArgsH pa) {
  const ProjDescH dd = pa.d[blockIdx.z];
  const int m0 = blockIdx.y * 128;
  if (m0 >= dd.M) return;
  const int n0 = blockIdx.x * 128;

  __shared__ __align__(16) unsigned char smem[32768];
  unsigned short* As = (unsigned short*)smem;
  unsigned short* Bs = As + 4096;
  unsigned short* Cs = (unsigned short*)smem;

  const int tid  = threadIdx.x;
  const int lane = tid & 63;
  const int w    = tid >> 6;
  const int wr   = (w >> 1) * 64;
  const int wc   = (w & 1) * 64;
  const int ql   = lane & 15;
  const int qd   = lane >> 4;

  f32x4 acc[4][4];
  for (int i = 0; i < 4; ++i)
    for (int j = 0; j < 4; ++j) acc[i][j] = (f32x4)(0.0f);

  const unsigned short* Xg = dd.X + (size_t)m0 * 1024;
  const unsigned short* Wg = dd.W + (size_t)n0 * 1024;

  for (int k0 = 0; k0 < 1024; k0 += 32) {
    __syncthreads();
    for (int half = 0; half < 2; ++half) {
      const int cb  = w * 128 + half * 64;
      const int c   = cb + lane;
      const int row = c >> 2;
      const int kcg = (c & 3) ^ (row & 3);
      GLOAD_LDS16(Xg + row * 1024 + k0 + kcg * 8, As + cb * 8);
      GLOAD_LDS16(Wg + row * 1024 + k0 + kcg * 8, Bs + cb * 8);
    }
    __syncthreads();

    half8 af[4], bf[4];
    for (int mt = 0; mt < 4; ++mt) {
      const int row = wr + mt * 16 + ql;
      af[mt] = *(const half8*)&As[row * 32 + ((qd ^ (row & 3)) << 3)];
    }
    for (int nt = 0; nt < 4; ++nt) {
      const int row = wc + nt * 16 + ql;
      bf[nt] = *(const half8*)&Bs[row * 32 + ((qd ^ (row & 3)) << 3)];
    }
    for (int mt = 0; mt < 4; ++mt)
      for (int nt = 0; nt < 4; ++nt)
        acc[mt][nt] = MFMA_F16(af[mt], bf[nt], acc[mt][nt], 0, 0, 0);
  }

  float bv[4];
  for (int nt = 0; nt < 4; ++nt)
    bv[nt] = dd.Bv[n0 + wc + nt * 16 + ql];

  __syncthreads();

  for (int mt = 0; mt < 4; ++mt) {
    for (int nt = 0; nt < 4; ++nt) {
      const int nl = wc + nt * 16 + ql;
      for (int r = 0; r < 4; ++r) {
        const int ml = wr + mt * 16 + qd * 4 + r;
        const int row = dd.mode == 1 ? nl : ml;
        const int col = dd.mode == 1 ? ml : nl;
        const float v = (acc[mt][nt][r] + bv[nt]) * dd.oscale;
        Cs[row * 128 + (((col >> 3) ^ (row & 7)) << 3) + (col & 7)] = f_to_f16u(v);
      }
    }
  }
  __syncthreads();

  copy_out_tile(Cs, dd.dst, tid, 256, m0 >> dd.lxsh, m0 & ((1 << dd.lxsh) - 1),
                n0 >> 6, dd.Ld, dd.soff, dd.mode);
}

// ---------------------------------------------------------------------------
// Fallback fp32-input GEMM for small ws_size (same output layouts)
// ---------------------------------------------------------------------------
struct ProjDesc {
  const float* X;
  const float* W;
  const float* Bv;
  unsigned short* dst;
  int M, lxsh, Ld, soff, mode;
  float oscale;
};
struct ProjArgs { ProjDesc d[12]; };

static __device__ __forceinline__ half8 cvt8sw(const float* base, int row, int g0) {
  const int sw = row & 7;
  const f32x4 a = *(const f32x4*)(base + (row * 8 + (g0 ^ sw)) * 4);
  const f32x4 b = *(const f32x4*)(base + (row * 8 + ((g0 + 1) ^ sw)) * 4);
  half8 h;
  h[0] = (_Float16)a[0]; h[1] = (_Float16)a[1];
  h[2] = (_Float16)a[2]; h[3] = (_Float16)a[3];
  h[4] = (_Float16)b[0]; h[5] = (_Float16)b[1];
  h[6] = (_Float16)b[2]; h[7] = (_Float16)b[3];
  return h;
}

__global__ __launch_bounds__(256) void proj_gemm_f32(ProjArgs pa) {
  const ProjDesc dd = pa.d[blockIdx.z];
  const int m0 = blockIdx.y * 128;
  if (m0 >= dd.M) return;
  const int n0 = blockIdx.x * 128;

  __shared__ __align__(16) unsigned char smem[32768];
  float* As = (float*)smem;
  float* Bs = As + 4096;
  unsigned short* Cs = (unsigned short*)smem;

  const int tid  = threadIdx.x;
  const int lane = tid & 63;
  const int w    = tid >> 6;
  const int wr   = (w >> 1) * 64;
  const int wc   = (w & 1) * 64;
  const int ql   = lane & 15;
  const int qd   = lane >> 4;

  f32x4 acc[4][4];
  for (int i = 0; i < 4; ++i)
    for (int j = 0; j < 4; ++j) acc[i][j] = (f32x4)(0.0f);

  const float* Xg = dd.X + (size_t)m0 * 1024;
  const float* Wg = dd.W + (size_t)n0 * 1024;

  for (int k0 = 0; k0 < 1024; k0 += 32) {
    __syncthreads();
    for (int j = 0; j < 4; ++j) {
      const int cb  = (j * 4 + w) * 64;
      const int c   = cb + lane;
      const int row = c >> 3;
      const int kcg = (c & 7) ^ (row & 7);
      GLOAD_LDS16(Xg + row * 1024 + k0 + kcg * 4, As + cb * 4);
      GLOAD_LDS16(Wg + row * 1024 + k0 + kcg * 4, Bs + cb * 4);
    }
    __syncthreads();

    half8 af[4], bf[4];
    for (int mt = 0; mt < 4; ++mt)
      af[mt] = cvt8sw(As, wr + mt * 16 + ql, qd * 2);
    for (int nt = 0; nt < 4; ++nt)
      bf[nt] = cvt8sw(Bs, wc + nt * 16 + ql, qd * 2);
    for (int mt = 0; mt < 4; ++mt)
      for (int nt = 0; nt < 4; ++nt)
        acc[mt][nt] = MFMA_F16(af[mt], bf[nt], acc[mt][nt], 0, 0, 0);
  }

  float bv[4];
  for (int nt = 0; nt < 4; ++nt)
    bv[nt] = dd.Bv[n0 + wc + nt * 16 + ql];

  __syncthreads();

  for (int mt = 0; mt < 4; ++mt) {
    for (int nt = 0; nt < 4; ++nt) {
      const int nl = wc + nt * 16 + ql;
      for (int r = 0; r < 4; ++r) {
        const int ml = wr + mt * 16 + qd * 4 + r;
        const int row = dd.mode == 1 ? nl : ml;
        const int col = dd.mode == 1 ? ml : nl;
        const float v = (acc[mt][nt][r] + bv[nt]) * dd.oscale;
        Cs[row * 128 + (((col >> 3) ^ (row & 7)) << 3) + (col & 7)] = f_to_f16u(v);
      }
    }
  }
  __syncthreads();

  copy_out_tile(Cs, dd.dst, tid, 256, m0 >> dd.lxsh, m0 & ((1 << dd.lxsh) - 1),
                n0 >> 6, dd.Ld, dd.soff, dd.mode);
}

// ---------------------------------------------------------------------------
// Flash attention v8: 64 q/block, KVBLK=64 (20 tiles), K/V dbuf LDS (2x16KB),
// XCD swizzle, base-2 softmax, key-mask bias in LDS. Same sync pattern and
// swizzles as v7 (layouts are per-16/32-key subtiles -> carry over).
// ---------------------------------------------------------------------------
__global__ __launch_bounds__(256) void attn_flash8(
    const unsigned short* __restrict__ Qa_v, const unsigned short* __restrict__ Qb_v,
    const unsigned short* __restrict__ K_v,  const unsigned short* __restrict__ V_vT,
    const unsigned short* __restrict__ Qa_t, const unsigned short* __restrict__ Qb_t,
    const unsigned short* __restrict__ K_t,  const unsigned short* __restrict__ V_tT,
    const int* __restrict__ vmask, const int* __restrict__ tmask,
    float* __restrict__ out_v, float* __restrict__ out_t) {
  __shared__ __align__(16) unsigned short KVs[16384];  // 2 bufs x 8192 halfs
  __shared__ __align__(16) float kb_s[1280];           // key bias (base-2)

  // XCD-contiguous swizzle: 1280 % 8 == 0 -> bijective. XCD x gets 8
  // consecutive bh -> 2.56MB K/V, L2-resident.
  const int bid = blockIdx.x;
  const int sid = (bid & 7) * 160 + (bid >> 3);
  const int bh  = sid / 20;
  const int sub = sid - bh * 20;

  const bool vside = sub < 16;
  const int  Lq    = vside ? 1024 : 256;
  const int  qblk  = vside ? sub : sub - 16;
  const unsigned short* Qa = vside ? Qa_v : Qa_t;
  const unsigned short* Qb = vside ? Qb_v : Qb_t;
  const unsigned short* K  = vside ? K_v  : K_t;
  const unsigned short* VT = vside ? V_vT : V_tT;
  const int* mq  = vside ? vmask : tmask;
  float*     out = vside ? out_v : out_t;

  const int b = bh >> 4;
  const int h = bh & 15;
  const int tid  = threadIdx.x;
  const int w    = tid >> 6;
  const int lane = tid & 63;
  const int ql = lane & 15, qd = lane >> 4;
  const int q0 = qblk * 64 + w * 16;

  const unsigned short* Kb = K  + (size_t)bh * 81920;
  const unsigned short* Vb = VT + (size_t)bh * 81920;

  // one-time: key-mask bias into LDS (covered by first tile's barrier)
  {
    const int* kmv = vmask + b * 1024;
    const int* kmt = tmask + b * 256;
    for (int i = tid; i < 1280; i += 256) {
      const int mk = (i < 1024) ? kmv[i] : kmt[i - 1024];
      kb_s[i] = mk ? 0.0f : NEGB;
    }
  }

  const int gsw  = (tid ^ ((tid >> 3) & 3)) * 8;  // per-lane global offs (halfs)
  const int wlds = w * 512;                       // wave-uniform LDS base (halfs)

  // 64-key tile: K = 4 contiguous 16-key subtiles (4096 halfs), V = 2
  // contiguous 32-key groups (4096 halfs). Chunk permutation c^((c>>3)&3)
  // is invariant under +256-chunk offsets (bit 8 doesn't reach bits 3-4).
#define STAGE8(nb, k0s)                                                     \
  do {                                                                      \
    const unsigned short* Kt_ = Kb + (size_t)((k0s) >> 4) * 1024;           \
    const unsigned short* Vt_ = Vb + (size_t)((k0s) >> 5) * 2048;           \
    unsigned short* Ld_ = KVs + (nb) * 8192 + wlds;                         \
    GLOAD_LDS16(Kt_ + gsw, Ld_);                                            \
    GLOAD_LDS16(Kt_ + 2048 + gsw, Ld_ + 2048);                              \
    GLOAD_LDS16(Vt_ + gsw, Ld_ + 4096);                                     \
    GLOAD_LDS16(Vt_ + 2048 + gsw, Ld_ + 6144);                              \
  } while (0)

  STAGE8(0, 0);  // prefetch tile 0 while we load Q

  const unsigned short* Qab = Qa + ((size_t)bh * Lq + q0) * 64;
  const unsigned short* Qbb = Qb + ((size_t)bh * Lq + q0) * 64;
  half8 aA[2], aB[2];
  for (int ks = 0; ks < 2; ++ks) {
    aA[ks] = *(const half8*)&Qab[ql * 64 + ks * 32 + qd * 8];
    aB[ks] = *(const half8*)&Qbb[ql * 64 + ks * 32 + qd * 8];
  }
  const int mqs = mq[b * Lq + q0 + ql];

  const int swc = (qd ^ ((ql >> 1) & 3)) * 8;  // read-side chunk XOR (halfs)

  float m = -1e30f, l = 0.0f;
  f32x4 o[4];
  for (int nt = 0; nt < 4; ++nt) o[nt] = (f32x4)(0.0f);

  int cur = 0;
  // tile body; QF = Q fragment pair (aA for vid keys, aB for txt keys)
#define TILE8(tt, QF)                                                       \
  {                                                                         \
    __syncthreads();                /* buf[cur] staged (vmcnt drained) */    \
    if ((tt) < 19) STAGE8(cur ^ 1, ((tt) + 1) * 64);                        \
    const unsigned short* Ls = KVs + cur * 8192;                            \
    half8 va[4], vb2[4];                                                    \
    for (int nt = 0; nt < 4; ++nt) {                                        \
      va[nt]  = *(const half8*)&Ls[4096 + (nt * 16 + ql) * 32 + swc];       \
      vb2[nt] = *(const half8*)&Ls[6144 + (nt * 16 + ql) * 32 + swc];       \
    }                                                                       \
    f32x4 sv[4];                                                            \
    for (int s = 0; s < 4; ++s) {                                           \
      f32x4 S = *(const f32x4*)&kb_s[(tt) * 64 + s * 16 + qd * 4];          \
      const unsigned short* Kt = Ls + s * 1024;                             \
      const half8 kf0 = *(const half8*)&Kt[ql * 32 + swc];                  \
      const half8 kf1 = *(const half8*)&Kt[512 + ql * 32 + swc];            \
      S = MFMA_F16(kf0, QF[0], S, 0, 0, 0);                                 \
      S = MFMA_F16(kf1, QF[1], S, 0, 0, 0);                                 \
      for (int r = 0; r < 4; ++r) sv[s][r] = mqs ? S[r] : NEGB;             \
    }                                                                       \
    const float b0 = fmaxf(fmaxf(sv[0][0], sv[0][1]), fmaxf(sv[0][2], sv[0][3])); \
    const float b1 = fmaxf(fmaxf(sv[1][0], sv[1][1]), fmaxf(sv[1][2], sv[1][3])); \
    const float b2 = fmaxf(fmaxf(sv[2][0], sv[2][1]), fmaxf(sv[2][2], sv[2][3])); \
    const float b3 = fmaxf(fmaxf(sv[3][0], sv[3][1]), fmaxf(sv[3][2], sv[3][3])); \
    float bm = fmaxf(fmaxf(b0, b1), fmaxf(b2, b3));                         \
    bm = fmaxf(bm, __shfl_xor(bm, 16, 64));                                 \
    bm = fmaxf(bm, __shfl_xor(bm, 32, 64));                                 \
    if (__any(bm > m)) {            /* THR=0 defer-max: exact */            \
      const float nm = fmaxf(m, bm);                                        \
      const float alpha = __builtin_amdgcn_exp2f(m - nm);                   \
      l *= alpha;                                                           \
      for (int nt = 0; nt < 4; ++nt)                                        \
        for (int r = 0; r < 4; ++r) o[nt][r] *= alpha;                      \
      m = nm;                                                               \
    }                                                                       \
    half4 pv[4];                                                            \
    float lsum = 0.0f;                                                      \
    for (int s = 0; s < 4; ++s)                                             \
      for (int r = 0; r < 4; ++r) {                                         \
        const float p = __builtin_amdgcn_exp2f(sv[s][r] - m);               \
        lsum += p;                                                          \
        pv[s][r] = (_Float16)p;                                             \
      }                                                                     \
    l += lsum;                                                              \
    for (int nt = 0; nt < 4; ++nt) {                                        \
      const half4 alo = __builtin_shufflevector(va[nt], va[nt], 0, 1, 2, 3);   \
      const half4 ahi = __builtin_shufflevector(va[nt], va[nt], 4, 5, 6, 7);   \
      const half4 blo = __builtin_shufflevector(vb2[nt], vb2[nt], 0, 1, 2, 3); \
      const half4 bhi = __builtin_shufflevector(vb2[nt], vb2[nt], 4, 5, 6, 7); \
      o[nt] = MFMA16_F16(alo, pv[0], o[nt], 0, 0, 0);                       \
      o[nt] = MFMA16_F16(ahi, pv[1], o[nt], 0, 0, 0);                       \
      o[nt] = MFMA16_F16(blo, pv[2], o[nt], 0, 0, 0);                       \
      o[nt] = MFMA16_F16(bhi, pv[3], o[nt], 0, 0, 0);                       \
    }                                                                       \
    cur ^= 1;                                                               \
  }

  for (int t = 0; t < 16; ++t) TILE8(t, aA);   // vid keys (16 x 64 = 1024)
  for (int t = 16; t < 20; ++t) TILE8(t, aB);  // txt keys (4 x 64 = 256)
#undef TILE8
#undef STAGE8

  // per-warp epilogue: reduce l over qd lanes (keys split across qd in S^T)
  l += __shfl_xor(l, 16, 64);
  l += __shfl_xor(l, 32, 64);
  const float inv = 0.125f / l;

  float* ob = out + ((size_t)(b * Lq + q0 + ql)) * 1024 + h * 64;
  for (int nt = 0; nt < 4; ++nt) {
    f32x4 r;
    for (int j = 0; j < 4; ++j) r[j] = o[nt][j] * inv;
    *(f32x4*)(ob + nt * 16 + qd * 4) = r;
  }
}

// ---------------------------------------------------------------------------
extern "C" void kernel_launch(void* const* d_in, const int* in_sizes, int n_in,
                              void* d_out, int out_size, void* d_ws, size_t ws_size,
                              hipStream_t stream) {
  const float* vid   = (const float*)d_in[0];
  const int*   vmask = (const int*)d_in[1];
  const float* txt   = (const float*)d_in[2];
  const int*   tmask = (const int*)d_in[3];
  const float* Wsrc[4] = {(const float*)d_in[4], (const float*)d_in[6],
                          (const float*)d_in[8], (const float*)d_in[10]};
  const float* Bsrc[4] = {(const float*)d_in[5], (const float*)d_in[7],
                          (const float*)d_in[9], (const float*)d_in[11]};

  const int DD = 1024 * 1024, Dm = 1024, MEG = 1048576;

  unsigned short* ws = (unsigned short*)d_ws;
  unsigned short* Qa_v = ws;                       // 4,194,304 halfs
  unsigned short* Qb_v = ws + 4194304;
  unsigned short* K_v  = ws + 8388608;             // 5,242,880
  unsigned short* V_vT = ws + 13631488;
  unsigned short* Qa_t = ws + 18874368;            // 1,048,576
  unsigned short* Qb_t = ws + 19922944;
  unsigned short* K_t  = ws + 20971520;            // 5,242,880
  unsigned short* V_tT = ws + 26214400;            // end 31,457,280
  unsigned short* Xv_h = ws + 31457280;            // 4,194,304 (dead after proj)
  unsigned short* Xt_h = ws + 35651584;            // 1,048,576
  unsigned short* Wh   = ws + 36700160;            // 12 MEG -> end 49,283,072

  const size_t need = (size_t)49283072 * 2;
  const bool use_h = ws_size >= need;

  if (use_h) {
    CvtArgs ca;
    ca.d[0] = CvtDesc{vid, Xv_h, 4194304 / 8};
    ca.d[1] = CvtDesc{txt, Xt_h, 1048576 / 8};
    for (int s = 0; s < 4; ++s)
      for (int j = 0; j < 3; ++j)
        ca.d[2 + s * 3 + j] = CvtDesc{Wsrc[s] + j * DD, Wh + (s * 3 + j) * MEG, DD / 8};
    cvt_fp16<<<dim3(256, 14), dim3(256), 0, stream>>>(ca);

    ProjArgsH pa;
    auto set = [&](int i, const unsigned short* X, int wi, const float* Bv,
                   unsigned short* dst, int M, int lxsh, int Ld, int soff, int mode,
                   float osc) {
      pa.d[i] = ProjDescH{X, Wh + wi * MEG, Bv, dst, M, lxsh, Ld, soff, mode, osc};
    };
    //    idx  X     Wi  bias          dst    M     lxsh Ld    soff  mode  oscale
    set(0,  Xv_h, 0,  Bsrc[0],          Qa_v, 4096, 10, 1024, 0,    0, LOG2E);
    set(1,  Xv_h, 1,  Bsrc[0] + Dm,     K_v,  4096, 10, 1280, 0,    2, 1.0f);
    set(2,  Xv_h, 2,  Bsrc[0] + 2 * Dm, V_vT, 4096, 10, 1280, 0,    1, 1.0f);
    set(3,  Xv_h, 3,  Bsrc[1],          Qb_v, 4096, 10, 1024, 0,    0, LOG2E);
    set(4,  Xt_h, 4,  Bsrc[1] + Dm,     K_v,  1024, 8,  1280, 1024, 2, 1.0f);
    set(5,  Xt_h, 5,  Bsrc[1] + 2 * Dm, V_vT, 1024, 8,  1280, 1024, 1, 1.0f);
    set(6,  Xt_h, 6,  Bsrc[2],          Qa_t, 1024, 8,  256,  0,    0, LOG2E);
    set(7,  Xv_h, 7,  Bsrc[2] + Dm,     K_t,  4096, 10, 1280, 0,    2, 1.0f);
    set(8,  Xv_h, 8,  Bsrc[2] + 2 * Dm, V_tT, 4096, 10, 1280, 0,    1, 1.0f);
    set(9,  Xt_h, 9,  Bsrc[3],          Qb_t, 1024, 8,  256,  0,    0, LOG2E);
    set(10, Xt_h, 10, Bsrc[3] + Dm,     K_t,  1024, 8,  1280, 1024, 2, 1.0f);
    set(11, Xt_h, 11, Bsrc[3] + 2 * Dm, V_tT, 1024, 8,  1280, 1024, 1, 1.0f);

    proj_gemm_h<<<dim3(8, 32, 12), dim3(256), 0, stream>>>(pa);
  } else {
    ProjArgs pa;
    auto set = [&](int i, const float* X, const float* W, const float* Bv,
                   unsigned short* dst, int M, int lxsh, int Ld, int soff, int mode,
                   float osc) {
      pa.d[i] = ProjDesc{X, W, Bv, dst, M, lxsh, Ld, soff, mode, osc};
    };
    set(0,  vid, Wsrc[0],          Bsrc[0],          Qa_v, 4096, 10, 1024, 0,    0, LOG2E);
    set(1,  vid, Wsrc[0] + DD,     Bsrc[0] + Dm,     K_v,  4096, 10, 1280, 0,    2, 1.0f);
    set(2,  vid, Wsrc[0] + 2 * DD, Bsrc[0] + 2 * Dm, V_vT, 4096, 10, 1280, 0,    1, 1.0f);
    set(3,  vid, Wsrc[1],          Bsrc[1],          Qb_v, 4096, 10, 1024, 0,    0, LOG2E);
    set(4,  txt, Wsrc[1] + DD,     Bsrc[1] + Dm,     K_v,  1024, 8,  1280, 1024, 2, 1.0f);
    set(5,  txt, Wsrc[1] + 2 * DD, Bsrc[1] + 2 * Dm, V_vT, 1024, 8,  1280, 1024, 1, 1.0f);
    set(6,  txt, Wsrc[2],          Bsrc[2],          Qa_t, 1024, 8,  256,  0,    0, LOG2E);
    set(7,  vid, Wsrc[2] + DD,     Bsrc[2] + Dm,     K_t,  4096, 10, 1280, 0,    2, 1.0f);
    set(8,  vid, Wsrc[2] + 2 * DD, Bsrc[2] + 2 * Dm, V_tT, 4096, 10, 1280, 0,    1, 1.0f);
    set(9,  txt, Wsrc[3],          Bsrc[3],          Qb_t, 1024, 8,  256,  0,    0, LOG2E);
    set(10, txt, Wsrc[3] + DD,     Bsrc[3] + Dm,     K_t,  1024, 8,  1280, 1024, 2, 1.0f);
    set(11, txt, Wsrc[3] + 2 * DD, Bsrc[3] + 2 * Dm, V_tT, 1024, 8,  1280, 1024, 1, 1.0f);

    proj_gemm_f32<<<dim3(8, 32, 12), dim3(256), 0, stream>>>(pa);
  }

  float* out_v = (float*)d_out;
  float* out_t = out_v + 4 * 1024 * 1024;
  attn_flash8<<<dim3(1280), dim3(256), 0, stream>>>(
      Qa_v, Qb_v, K_v, V_vT, Qa_t, Qb_t, K_t, V_tT,
      vmask, tmask, out_v, out_t);
}